// Round 2
// baseline (580.740 us; speedup 1.0000x reference)
//
#include <hip/hip_runtime.h>
#include <stdint.h>

#define NGRAPHS 4096
#define DIN 128
#define DOUT 256

// One block per (graph g, node-type t). Phase A: segment-sum x rows (fp32,
// [N,128]) into 128 fp32 column sums via LDS reduce, scale by 1/n.
// Phase B: out[g, t*256 + j] = mean . W[:,j] + b[j]  (fp32 out).
// Empty segments (n==0) write zeros per reference semantics (bias NOT added,
// since reference divides the zero SUM, it never adds bias to empty graphs'
// pooled value... actually reference computes y=xW+b per NODE then pools;
// empty graph => sum of zero nodes = 0, count clamped to 1 => exact zeros).
__global__ __launch_bounds__(256)
void seg_encode_kernel(const float* __restrict__ x_a, const float* __restrict__ W_a,
                       const float* __restrict__ b_a, const int* __restrict__ ptr_a,
                       const float* __restrict__ x_b, const float* __restrict__ W_b,
                       const float* __restrict__ b_b, const int* __restrict__ ptr_b,
                       float* __restrict__ out) {
    const int g   = blockIdx.x;
    const int t   = blockIdx.y;           // 0 = type a, 1 = type b
    const int tid = threadIdx.x;

    const float* __restrict__ x    = t ? x_b  : x_a;
    const float* __restrict__ W    = t ? W_b  : W_a;
    const float* __restrict__ bias = t ? b_b  : b_a;
    const int*   __restrict__ ptr  = t ? ptr_b : ptr_a;

    const int s = ptr[g];
    const int e = ptr[g + 1];
    const int n = e - s;

    float* __restrict__ orow = out + (size_t)g * (2 * DOUT) + t * DOUT;

    if (n == 0) {
        orow[tid] = 0.0f;   // exact zeros for empty segments
        return;
    }

    __shared__ float red[8][DIN];    // 4 KB
    __shared__ float mean[DIN];      // 512 B

    // ---- Phase A: segment column sums ----
    const int slot = tid & 31;   // which 16B chunk of the 512B row (32 chunks)
    const int r    = tid >> 5;   // row-within-tile, 0..7

    float4 acc = make_float4(0.f, 0.f, 0.f, 0.f);

    const float* __restrict__ xs = x + (size_t)slot * 4;
    for (int i = s + r; i < e; i += 8) {
        float4 v = *(const float4*)(xs + (size_t)i * DIN);
        acc.x += v.x; acc.y += v.y; acc.z += v.z; acc.w += v.w;
    }

    red[r][slot * 4 + 0] = acc.x;
    red[r][slot * 4 + 1] = acc.y;
    red[r][slot * 4 + 2] = acc.z;
    red[r][slot * 4 + 3] = acc.w;
    __syncthreads();

    if (tid < DIN) {
        float sum = 0.0f;
#pragma unroll
        for (int rr = 0; rr < 8; ++rr) sum += red[rr][tid];
        mean[tid] = sum * (1.0f / (float)n);
    }
    __syncthreads();

    // ---- Phase B: 1x128 @ 128x256 + bias, one output column per thread ----
    float o = bias[tid];
    const float* __restrict__ wcol = W + tid;   // column-j walk, stride DOUT
#pragma unroll 8
    for (int k = 0; k < DIN; ++k) {
        o += mean[k] * wcol[(size_t)k * DOUT];
    }
    orow[tid] = o;
}

extern "C" void kernel_launch(void* const* d_in, const int* in_sizes, int n_in,
                              void* d_out, int out_size, void* d_ws, size_t ws_size,
                              hipStream_t stream) {
    const float* x_a  = (const float*)d_in[0];
    const float* W_a  = (const float*)d_in[1];
    const float* b_a  = (const float*)d_in[2];
    const float* x_b  = (const float*)d_in[3];
    const float* W_b  = (const float*)d_in[4];
    const float* b_b  = (const float*)d_in[5];
    const int*   ptr_a = (const int*)d_in[6];
    const int*   ptr_b = (const int*)d_in[7];
    float* out = (float*)d_out;

    dim3 grid(NGRAPHS, 2);
    seg_encode_kernel<<<grid, 256, 0, stream>>>(x_a, W_a, b_a, ptr_a,
                                                x_b, W_b, b_b, ptr_b, out);
}